// Round 17
// baseline (87.012 us; speedup 1.0000x reference)
//
#include <hip/hip_runtime.h>
#include <math.h>

// GptOssRouter: T=16384, H=2880, E=128, K=4.
// K0: pre-split w (fp32 -> bf16 h/l, trunc-exact) into d_ws as MFMA B-frag
//     tiles. K1: 32 tok x 128 exp per block, grid=512. x staged via
//     global_load_lds (HW VMEM queue, no VGPR liveness fight), 4 LDS fp32
//     buffers, issue depth 3. RACE FIX vs r16: the GLL issue for chunk cc+3
//     (which reuses the buffer read at phase cc-1) is placed AFTER the phase
//     barrier, so all readers have retired. Counted vmcnt(12) + raw s_barrier
//     per phase; compiler's own w-VGPR waits provide the x-completion backstop
//     (w loads are FIFO-newer than the x loads they guard).
//     Math: 3-pass split-bf16 MFMA xh*wh+xh*wl+xl*wh (err ~1e-5); fused
//     stripe-top8 + certified-gap (TAU=2.5e-4) -> fast fp32 softmax; rare
//     fp64 rescore (order == float64 numpy reference).

#define T_TOK 16384
#define HDIM  2880
#define EEXP  128
#define KTOP  4

#define TM   32
#define NT   256
#define KC   64              // floats per chunk
#define NCH  45
#define XBUF 8192            // 32 rows * 256 B fp32
#define TAU  2.5e-4f

typedef __attribute__((ext_vector_type(8))) short bf16x8;
typedef __attribute__((ext_vector_type(4))) float f32x4;

#define MFMA(a, b, c) __builtin_amdgcn_mfma_f32_16x16x32_bf16((a), (b), (c), 0, 0, 0)

#define GLL(g, l) __builtin_amdgcn_global_load_lds(                        \
        (__attribute__((address_space(1))) void*)(g),                      \
        (__attribute__((address_space(3))) void*)(l), 16, 0, 0)

// ---------------- K0: w pre-split into fragment-tiled bf16 h/l -------------
__global__ __launch_bounds__(256) void w_split(
    const float* __restrict__ w, char* __restrict__ wp)
{
    const int gid  = blockIdx.x * 256 + threadIdx.x;   // 46080 total
    const int lane = gid & 63;
    const int q    = gid >> 6;        // 0..719
    const int ks   = q & 1;
    const int q2   = q >> 1;          // 0..359
    const int c    = q2 % NCH;
    const int F    = q2 / NCH;        // 0..7
    const int e    = F * 16 + (lane & 15);
    const int k0   = c * 64 + ks * 32 + (lane >> 4) * 8;

    const float* src = w + (size_t)e * HDIM + k0;
    float4 v0 = *(const float4*)(src);
    float4 v1 = *(const float4*)(src + 4);
    float vv[8] = {v0.x, v0.y, v0.z, v0.w, v1.x, v1.y, v1.z, v1.w};
    union { unsigned short s[8]; uint4 u; } H, L;
#pragma unroll
    for (int j = 0; j < 8; ++j) {
        unsigned u = __float_as_uint(vv[j]);
        H.s[j] = (unsigned short)(u >> 16);
        float rr = vv[j] - __uint_as_float(u & 0xffff0000u);
        L.s[j] = (unsigned short)(__float_as_uint(rr) >> 16);
    }
    const int tile = ((F * NCH + c) * 2 + ks) * 2;     // p=0 (h); l at +1
    *(uint4*)(wp + (size_t)tile * 1024 + lane * 16)       = H.u;
    *(uint4*)(wp + (size_t)(tile + 1) * 1024 + lane * 16) = L.u;
}

// in-register split: 8 floats -> h bf16x8 (trunc) + l bf16x8 (trunc of resid)
static __device__ __forceinline__ void split8(float4 v0, float4 v1,
                                              bf16x8* h8, bf16x8* l8) {
    union { float4 f; unsigned u[4]; } a, b; a.f = v0; b.f = v1;
    union { unsigned u[4]; bf16x8 v; } H, L;
    H.u[0] = __builtin_amdgcn_perm(a.u[1], a.u[0], 0x07060302u);
    H.u[1] = __builtin_amdgcn_perm(a.u[3], a.u[2], 0x07060302u);
    H.u[2] = __builtin_amdgcn_perm(b.u[1], b.u[0], 0x07060302u);
    H.u[3] = __builtin_amdgcn_perm(b.u[3], b.u[2], 0x07060302u);
    float r0 = v0.x - __uint_as_float(a.u[0] & 0xffff0000u);
    float r1 = v0.y - __uint_as_float(a.u[1] & 0xffff0000u);
    float r2 = v0.z - __uint_as_float(a.u[2] & 0xffff0000u);
    float r3 = v0.w - __uint_as_float(a.u[3] & 0xffff0000u);
    float r4 = v1.x - __uint_as_float(b.u[0] & 0xffff0000u);
    float r5 = v1.y - __uint_as_float(b.u[1] & 0xffff0000u);
    float r6 = v1.z - __uint_as_float(b.u[2] & 0xffff0000u);
    float r7 = v1.w - __uint_as_float(b.u[3] & 0xffff0000u);
    L.u[0] = __builtin_amdgcn_perm(__float_as_uint(r1), __float_as_uint(r0), 0x07060302u);
    L.u[1] = __builtin_amdgcn_perm(__float_as_uint(r3), __float_as_uint(r2), 0x07060302u);
    L.u[2] = __builtin_amdgcn_perm(__float_as_uint(r5), __float_as_uint(r4), 0x07060302u);
    L.u[3] = __builtin_amdgcn_perm(__float_as_uint(r7), __float_as_uint(r6), 0x07060302u);
    *h8 = H.v; *l8 = L.v;
}

// ---------------- K1: fused GEMM + selection --------------------------------
__global__ __launch_bounds__(NT, 2) void router_fused(
    const float* __restrict__ x, const char* __restrict__ wp,
    const float* __restrict__ w, const float* __restrict__ bias,
    float* __restrict__ out)
{
    __shared__ char smem[32768];        // 4 x-buffers (8KB) / epilogue overlay
    const int tid  = threadIdx.x;
    const int tok0 = blockIdx.x * TM;
    const int lane = tid & 63;
    const int wv   = tid >> 6;          // expert 32-group 0..3
    const int r    = lane & 15;
    const int g    = lane >> 4;

    // --- x staging via global_load_lds: inst m = wv*2+i covers rows m*4..m*4+3
    // LDS dest linear (base + lane*16). Global source pre-swizzled so phys
    // slot s holds logical slot s^(row&7) (both-sides rule).
    const int m0 = wv * 2, m1 = wv * 2 + 1;
    const int sr0 = m0 * 4 + (lane >> 4);
    const int sr1 = m1 * 4 + (lane >> 4);
    const float* gp0 = x + (size_t)(tok0 + sr0) * HDIM + (((lane & 15) ^ (sr0 & 7)) << 2);
    const float* gp1 = x + (size_t)(tok0 + sr1) * HDIM + (((lane & 15) ^ (sr1 & 7)) << 2);
    char* lbs0 = smem + m0 * 1024;
    char* lbs1 = smem + m1 * 1024;

    // a-frag read offsets: [tf][ks][j] -> phys slot = (ks*8+g*2+j) ^ (r&7)
    int aof[2][2][2];
#pragma unroll
    for (int tf = 0; tf < 2; ++tf) {
        int row = tf * 16 + r;
#pragma unroll
        for (int ks = 0; ks < 2; ++ks)
#pragma unroll
            for (int j = 0; j < 2; ++j)
                aof[tf][ks][j] = row * 256 + (((ks * 8 + g * 2 + j) ^ (r & 7)) << 4);
    }

    f32x4 a00 = {0.f, 0.f, 0.f, 0.f}, a01 = a00, a10 = a00, a11 = a00;

#define ISSUEX(cc, bi) do {                                           \
        GLL(gp0 + (size_t)(cc) * KC, lbs0 + (bi) * XBUF);             \
        GLL(gp1 + (size_t)(cc) * KC, lbs1 + (bi) * XBUF);             \
    } while (0)

    // w frag tiles: idx = F2*4 + ks*2 + p
#define LOADW(W, cc) do {                                             \
        _Pragma("unroll")                                             \
        for (int F2 = 0; F2 < 2; ++F2)                                \
        _Pragma("unroll")                                             \
        for (int ks_ = 0; ks_ < 2; ++ks_)                             \
        _Pragma("unroll")                                             \
        for (int p_ = 0; p_ < 2; ++p_)                                \
            W[F2*4 + ks_*2 + p_] = *(const bf16x8*)(wp +              \
                (size_t)((((wv*2 + F2) * NCH + (cc)) * 2 + ks_) * 2 + p_) * 1024 \
                + lane * 16); } while (0)

#define MFMA_CHUNK(bp, W) do {                                        \
        _Pragma("unroll")                                             \
        for (int ks_ = 0; ks_ < 2; ++ks_) {                           \
            float4 xv00 = *(const float4*)((bp) + aof[0][ks_][0]);    \
            float4 xv01 = *(const float4*)((bp) + aof[0][ks_][1]);    \
            float4 xv10 = *(const float4*)((bp) + aof[1][ks_][0]);    \
            float4 xv11 = *(const float4*)((bp) + aof[1][ks_][1]);    \
            bf16x8 ah0, al0, ah1, al1;                                \
            split8(xv00, xv01, &ah0, &al0);                           \
            split8(xv10, xv11, &ah1, &al1);                           \
            bf16x8 bh0 = W[ks_*2],     bl0 = W[ks_*2 + 1];            \
            bf16x8 bh1 = W[4 + ks_*2], bl1 = W[4 + ks_*2 + 1];        \
            a00 = MFMA(ah0, bh0, a00); a01 = MFMA(ah0, bh1, a01);     \
            a10 = MFMA(ah1, bh0, a10); a11 = MFMA(ah1, bh1, a11);     \
            a00 = MFMA(ah0, bl0, a00); a01 = MFMA(ah0, bl1, a01);     \
            a10 = MFMA(ah1, bl0, a10); a11 = MFMA(ah1, bl1, a11);     \
            a00 = MFMA(al0, bh0, a00); a01 = MFMA(al0, bh1, a01);     \
            a10 = MFMA(al1, bh0, a10); a11 = MFMA(al1, bh1, a11);     \
        } } while (0)

    // Phase cc: wait (x(cc) landed for ALL waves after barrier), THEN issue
    // the buffer-reusing GLL (after readers retired), then w, then MFMA.
#define PHASE(cc, bi_rd, WC, WN) do {                                 \
        asm volatile("s_waitcnt vmcnt(12)" ::: "memory");             \
        __builtin_amdgcn_sched_barrier(0);                            \
        __builtin_amdgcn_s_barrier();                                 \
        __builtin_amdgcn_sched_barrier(0);                            \
        if ((cc) + 3 < NCH) ISSUEX((cc) + 3, ((cc) + 3) & 3);         \
        if ((cc) + 1 < NCH) LOADW(WN, (cc) + 1);                      \
        MFMA_CHUNK(smem + (bi_rd) * XBUF, WC);                        \
    } while (0)

    bf16x8 wA[8], wB[8];

    // prologue: x chunks 0..2 into bufs 0..2 (HW queue), w0 into wA
    ISSUEX(0, 0); ISSUEX(1, 1); ISSUEX(2, 2);
    LOADW(wA, 0);

    for (int it = 0; it < 11; ++it) {
        int c = it * 4;
        PHASE(c + 0, 0, wA, wB);
        PHASE(c + 1, 1, wB, wA);
        PHASE(c + 2, 2, wA, wB);
        PHASE(c + 3, 3, wB, wA);
    }
    PHASE(44, 0, wA, wB);                 // final chunk
    __syncthreads();                      // full drain before overlay

    // -------- logits(+bias) -> LDS [32][130] --------------------------------
    float* logitsL = (float*)smem;
    const float bv0 = bias[wv * 32 + r];
    const float bv1 = bias[wv * 32 + 16 + r];
#pragma unroll
    for (int q = 0; q < 4; ++q) {
        int m0q = g * 4 + q, m1q = m0q + 16;
        int e0 = wv * 32 + r, e1 = e0 + 16;
        logitsL[m0q * 130 + e0] = a00[q] + bv0;
        logitsL[m0q * 130 + e1] = a01[q] + bv1;
        logitsL[m1q * 130 + e0] = a10[q] + bv0;
        logitsL[m1q * 130 + e1] = a11[q] + bv1;
    }
    float*  cvf = (float*) (smem + 16640);   // [32][8]
    int*    cie = (int*)   (smem + 17664);   // [32][8]
    int*    flg = (int*)   (smem + 18688);   // [32]
    double* svd = (double*)(smem + 18816);   // [32][4]
    int*    sid = (int*)   (smem + 19840);   // [32][4]
    double* cvd = (double*)(smem + 20352);   // [8]
    __syncthreads();

    // -------- stripe top-8: thread (t, s) scans experts [s*16, s*16+16) -----
    {
        const int t = tid >> 3, s = tid & 7;
        float v[8]; int id[8];
#pragma unroll
        for (int k = 0; k < 8; ++k) { v[k] = -3.4e38f; id[k] = 0x7fffffff; }
        for (int jj = 0; jj < 16; ++jj) {
            float lv = logitsL[t * 130 + s * 16 + jj];
            int   e  = s * 16 + jj;
            bool gt[8];
#pragma unroll
            for (int k = 0; k < 8; ++k)
                gt[k] = (lv > v[k]) || (lv == v[k] && e < id[k]);
#pragma unroll
            for (int k = 7; k >= 1; --k)
                if (gt[k - 1]) { v[k] = v[k - 1]; id[k] = id[k - 1]; }
#pragma unroll
            for (int k = 0; k < 8; ++k) {
                bool put = gt[k] && (k == 0 || !gt[k - 1]);
                if (put) { v[k] = lv; id[k] = e; }
            }
        }
#pragma unroll
        for (int rd = 0; rd < 8; ++rd) {
            float hv = v[0]; int hi = id[0];
#pragma unroll
            for (int off = 1; off < 8; off <<= 1) {
                float ov = __shfl_xor(hv, off);
                int   oi = __shfl_xor(hi, off);
                if (ov > hv || (ov == hv && oi < hi)) { hv = ov; hi = oi; }
            }
            if (s == 0) { cvf[t * 8 + rd] = hv; cie[t * 8 + rd] = hi; }
            bool mine = (v[0] == hv) && (id[0] == hi);
            if (mine) {
#pragma unroll
                for (int k = 0; k < 7; ++k) { v[k] = v[k + 1]; id[k] = id[k + 1]; }
                v[7] = -3.4e38f; id[7] = 0x7fffffff;
            }
        }
    }
    __syncthreads();

    // -------- certified-gap test + fast-path fill ---------------------------
    if (tid < TM) {
        float gmin = 3.4e38f;
#pragma unroll
        for (int k = 0; k < 4; ++k)
            gmin = fminf(gmin, cvf[tid * 8 + k] - cvf[tid * 8 + k + 1]);
        flg[tid] = (gmin < TAU);
    }
    if (tid < 128) {
        int t2 = tid >> 2, k = tid & 3;
        svd[t2 * 4 + k] = (double)cvf[t2 * 8 + k];
        sid[t2 * 4 + k] = cie[t2 * 8 + k];
    }
    __syncthreads();

    // -------- rare slow path: fp64 rescore (2 candidates per wave) ----------
    for (int ts = 0; ts < TM; ++ts) {
        if (!flg[ts]) continue;              // uniform across block
#pragma unroll
        for (int h2 = 0; h2 < 2; ++h2) {
            const int cand = wv * 2 + h2;
            const int ce = cie[ts * 8 + cand];
            const float4* xr = (const float4*)(x + (size_t)(tok0 + ts) * HDIM);
            const float4* wr = (const float4*)(w + (size_t)ce * HDIM);
            double q0 = 0.0, q1 = 0.0, q2 = 0.0, q3 = 0.0;
            for (int i2 = 0; i2 < 12; ++i2) {
                int fi = lane + i2 * 64;
                if (fi < HDIM / 4) {
                    float4 xv = xr[fi];
                    float4 wv4 = wr[fi];
                    q0 = fma((double)xv.x, (double)wv4.x, q0);
                    q1 = fma((double)xv.y, (double)wv4.y, q1);
                    q2 = fma((double)xv.z, (double)wv4.z, q2);
                    q3 = fma((double)xv.w, (double)wv4.w, q3);
                }
            }
            double accd = (q0 + q2) + (q1 + q3);
#pragma unroll
            for (int off = 32; off > 0; off >>= 1)
                accd += __shfl_xor(accd, off);
            if (lane == 0) cvd[cand] = accd + (double)bias[ce];
        }
        __syncthreads();
        if (tid < 8) {                        // fp64 rank among 8 candidates
            double mv = cvd[tid]; int mi2 = cie[ts * 8 + tid];
            int rk = 0;
#pragma unroll
            for (int j2 = 0; j2 < 8; ++j2) {
                double oj = cvd[j2];
                rk += (oj > mv) || (oj == mv && cie[ts * 8 + j2] < mi2);
            }
            if (rk < 4) { svd[ts * 4 + rk] = mv; sid[ts * 4 + rk] = mi2; }
        }
        __syncthreads();
    }

    // -------- softmax + outputs ---------------------------------------------
    float* srow = (float*)smem;              // [32][128], overlays dead logits
    float4 z4 = make_float4(0.f, 0.f, 0.f, 0.f);
#pragma unroll
    for (int i = 0; i < 4; ++i)
        ((float4*)srow)[tid + i * NT] = z4;
    __syncthreads();

    if (tid < TM) {
        double m  = svd[tid * 4];
        double e0 = exp(svd[tid * 4 + 0] - m), e1 = exp(svd[tid * 4 + 1] - m);
        double e2 = exp(svd[tid * 4 + 2] - m), e3 = exp(svd[tid * 4 + 3] - m);
        double inv = 1.0 / ((e0 + e1) + (e2 + e3));
        float* oidx = out + (size_t)T_TOK * EEXP + (size_t)(tok0 + tid) * KTOP;
        int i0 = sid[tid * 4 + 0], i1 = sid[tid * 4 + 1];
        int i2 = sid[tid * 4 + 2], i3 = sid[tid * 4 + 3];
        oidx[0] = (float)i0; oidx[1] = (float)i1;
        oidx[2] = (float)i2; oidx[3] = (float)i3;
        srow[tid * EEXP + i0] = (float)(e0 * inv);
        srow[tid * EEXP + i1] = (float)(e1 * inv);
        srow[tid * EEXP + i2] = (float)(e2 * inv);
        srow[tid * EEXP + i3] = (float)(e3 * inv);
    }
    __syncthreads();

    float4* orow = (float4*)(out + (size_t)tok0 * EEXP);
#pragma unroll
    for (int i = 0; i < 4; ++i)
        orow[tid + i * NT] = ((float4*)srow)[tid + i * NT];
}

extern "C" void kernel_launch(void* const* d_in, const int* in_sizes, int n_in,
                              void* d_out, int out_size, void* d_ws, size_t ws_size,
                              hipStream_t stream) {
    const float* x    = (const float*)d_in[0];
    const float* w    = (const float*)d_in[1];
    const float* bias = (const float*)d_in[2];
    float* out        = (float*)d_out;
    char*  wp         = (char*)d_ws;   // 1440 KiB (8*45*2*2 tiles * 1KB)

    hipLaunchKernelGGL(w_split, dim3(180), dim3(256), 0, stream, w, wp);
    hipLaunchKernelGGL(router_fused, dim3(T_TOK / TM), dim3(NT), 0, stream,
                       x, wp, w, bias, out);
}

// Round 18
// 81.762 us; speedup vs baseline: 1.0642x; 1.0642x over previous
//
#include <hip/hip_runtime.h>
#include <math.h>

// GptOssRouter: T=16384, H=2880, E=128, K=4.
// r18 = r12 skeleton (best: 80.2us) with ONE change: 32x32x16 MFMA instead of
// 16x16x32 -> 12 MFMAs/chunk/wave instead of 24 (same FLOPs, same bytes).
// Tests the empirical law "time ~ per-wave MFMA instruction count"
// (r5: 6/chunk=43us; r15: 24/chunk=80us; r9: 18/chunk=133us w/ LDS-w).
// K0: pre-split w (fp32 -> bf16 h/l, trunc-exact) into d_ws as 32x32x16
//     B-frag tiles: tile(F2,t,p)[lane] = 8 bf16 of
//     w[F2*32+(lane&31)][t*16+(lane>>5)*8 ...].
// K1: 32 tok x 128 exp per block, grid=512; wave = 32tok x 32exp, ONE f32x16
//     acc; x split h/l into swizzled LDS (3 bufs, depth-3 reg prefetch).
//     3-pass split-bf16: xh*wh + xh*wl + xl*wh (err ~1e-5). Fused stripe-top8
//     + certified-gap (TAU=2.5e-4) -> fast fp32 softmax; rare fp64 rescore
//     (order == float64 numpy reference).

#define T_TOK 16384
#define HDIM  2880
#define EEXP  128
#define KTOP  4

#define TM   32
#define NT   256
#define KC   64
#define NCH  (HDIM / KC)     // 45 = 15 * 3
#define NT16 (HDIM / 16)     // 180 k16-steps
#define XBUF 8192            // 32 rows * 256 B
#define TAU  2.5e-4f

typedef __attribute__((ext_vector_type(8)))  short bf16x8;
typedef __attribute__((ext_vector_type(4)))  float f32x4;
typedef __attribute__((ext_vector_type(16))) float f32x16;

#define MFMA32(a, b, c) __builtin_amdgcn_mfma_f32_32x32x16_bf16((a), (b), (c), 0, 0, 0)

// ---------------- K0: w pre-split into 32x32x16 B-frag tiles ----------------
__global__ __launch_bounds__(256) void w_split(
    const float* __restrict__ w, char* __restrict__ wp)
{
    const int gid  = blockIdx.x * 256 + threadIdx.x;   // 46080 = 720 q * 64
    const int lane = gid & 63;
    const int q    = gid >> 6;        // 0..719
    const int t    = q % NT16;        // k16-step 0..179
    const int F2   = q / NT16;        // expert-32-group 0..3
    const int e    = F2 * 32 + (lane & 31);
    const int k0   = t * 16 + (lane >> 5) * 8;

    const float* src = w + (size_t)e * HDIM + k0;
    float4 v0 = *(const float4*)(src);
    float4 v1 = *(const float4*)(src + 4);
    float vv[8] = {v0.x, v0.y, v0.z, v0.w, v1.x, v1.y, v1.z, v1.w};
    union { unsigned short s[8]; uint4 u; } H, L;
#pragma unroll
    for (int j = 0; j < 8; ++j) {
        unsigned u = __float_as_uint(vv[j]);
        H.s[j] = (unsigned short)(u >> 16);
        float rr = vv[j] - __uint_as_float(u & 0xffff0000u);
        L.s[j] = (unsigned short)(__float_as_uint(rr) >> 16);
    }
    const int tile = (F2 * NT16 + t) * 2;              // h; l at +1
    *(uint4*)(wp + (size_t)tile * 1024 + lane * 16)       = H.u;
    *(uint4*)(wp + (size_t)(tile + 1) * 1024 + lane * 16) = L.u;
}

// x split: v = h + l (h = trunc_bf16(v), l = trunc_bf16(v - h), both exact);
// h 8B at swizzled slot, l at +128 within the 256B row.
static __device__ __forceinline__ void split_write256(char* base, int off, float4 v) {
    union { float4 v4; unsigned u[4]; } uv; uv.v4 = v;
    unsigned h01 = __builtin_amdgcn_perm(uv.u[1], uv.u[0], 0x07060302u);
    unsigned h23 = __builtin_amdgcn_perm(uv.u[3], uv.u[2], 0x07060302u);
    float r0 = v.x - __uint_as_float(uv.u[0] & 0xffff0000u);
    float r1 = v.y - __uint_as_float(uv.u[1] & 0xffff0000u);
    float r2 = v.z - __uint_as_float(uv.u[2] & 0xffff0000u);
    float r3 = v.w - __uint_as_float(uv.u[3] & 0xffff0000u);
    unsigned l01 = __builtin_amdgcn_perm(__float_as_uint(r1), __float_as_uint(r0), 0x07060302u);
    unsigned l23 = __builtin_amdgcn_perm(__float_as_uint(r3), __float_as_uint(r2), 0x07060302u);
    uint2 hw; hw.x = h01; hw.y = h23;
    uint2 lw; lw.x = l01; lw.y = l23;
    *(uint2*)(base + off)       = hw;
    *(uint2*)(base + off + 128) = lw;
}

// ---------------- K1: fused GEMM + selection --------------------------------
__global__ __launch_bounds__(NT, 2) void router_fused(
    const float* __restrict__ x, const char* __restrict__ wp,
    const float* __restrict__ w, const float* __restrict__ bias,
    float* __restrict__ out)
{
    __shared__ char smem[3 * XBUF];     // 24576 B
    const int tid  = threadIdx.x;
    const int tok0 = blockIdx.x * TM;
    const int lane = tid & 63;
    const int wv   = tid >> 6;          // expert 32-group 0..3

    char* xb0 = smem;
    char* xb1 = smem + XBUF;
    char* xb2 = smem + 2 * XBUF;

    // x staging map: 512 float4 / 256 thr = 2 per thread (identical to r12)
    int xoff[2];
    const float* xptr[2];
#pragma unroll
    for (int i = 0; i < 2; ++i) {
        int f = tid + i * NT;
        int row = f >> 4, c4 = f & 15;
        xoff[i] = row * 256 + ((((c4 >> 1) ^ (row & 7)) << 4) | ((c4 & 1) << 3));
        xptr[i] = x + (size_t)(tok0 + row) * HDIM + c4 * 4;
    }

    // A-frag read offsets (32x32x16): lane holds tok=lane&31,
    // k = ks*16 + (lane>>5)*8 + j  -> logical slot ks*2+(lane>>5), XOR row&7.
    int aof[4];
    {
        int row = lane & 31;
#pragma unroll
        for (int ks = 0; ks < 4; ++ks)
            aof[ks] = row * 256 + (((ks * 2 + (lane >> 5)) ^ (row & 7)) << 4);
    }

    f32x16 acc;
#pragma unroll
    for (int i = 0; i < 16; ++i) acc[i] = 0.f;

#define LOADX(pf, cc) do {                                            \
        pf[0] = *(const float4*)(xptr[0] + (cc) * KC);                \
        pf[1] = *(const float4*)(xptr[1] + (cc) * KC); } while (0)

#define WRITEX(pf, bb) do {                                           \
        split_write256((bb), xoff[0], pf[0]);                         \
        split_write256((bb), xoff[1], pf[1]); } while (0)

    // w frag tiles for wave's expert group: W[ks*2+p], chunk cc covers
    // k16-steps cc*4..cc*4+3.
#define LOADW(W, cc) do {                                             \
        _Pragma("unroll")                                             \
        for (int ks_ = 0; ks_ < 4; ++ks_)                             \
        _Pragma("unroll")                                             \
        for (int p_ = 0; p_ < 2; ++p_)                                \
            W[ks_*2 + p_] = *(const bf16x8*)(wp +                     \
                (size_t)((wv * NT16 + (cc) * 4 + ks_) * 2 + p_) * 1024 \
                + lane * 16); } while (0)

#define MFMA_CHUNK(cb, W) do {                                        \
        _Pragma("unroll")                                             \
        for (int ks_ = 0; ks_ < 4; ++ks_) {                           \
            bf16x8 ah = *(const bf16x8*)((cb) + aof[ks_]);            \
            bf16x8 al = *(const bf16x8*)((cb) + aof[ks_] + 128);      \
            acc = MFMA32(ah, W[ks_*2],     acc);                      \
            acc = MFMA32(ah, W[ks_*2 + 1], acc);                      \
            acc = MFMA32(al, W[ks_*2],     acc);                      \
        } } while (0)

    float4 pfA[2], pfB[2], pfC[2];
    bf16x8 wA[8], wB[8], wC[8];

    // prologue: chunks 0..2 in regs, chunk 0 -> xb0; w chunks 0,1 in regs
    LOADX(pfA, 0); LOADX(pfB, 1); LOADX(pfC, 2);
    LOADW(wA, 0); LOADW(wB, 1);
    WRITEX(pfA, xb0);
    __syncthreads();

    for (int c = 0; c < NCH; c += 3) {
        // ---- phase 0: chunk c on xb0 / wA --------------------------------
        if (c + 3 < NCH) LOADX(pfA, c + 3);
        LOADW(wC, c + 2);
        MFMA_CHUNK(xb0, wA);
        WRITEX(pfB, xb1);                 // chunk c+1 (loaded 3 phases ago)
        __syncthreads();
        // ---- phase 1: chunk c+1 on xb1 / wB ------------------------------
        if (c + 3 < NCH) LOADW(wA, c + 3);
        if (c + 4 < NCH) LOADX(pfB, c + 4);
        MFMA_CHUNK(xb1, wB);
        WRITEX(pfC, xb2);                 // chunk c+2
        __syncthreads();
        // ---- phase 2: chunk c+2 on xb2 / wC ------------------------------
        if (c + 4 < NCH) LOADW(wB, c + 4);
        if (c + 5 < NCH) LOADX(pfC, c + 5);
        MFMA_CHUNK(xb2, wC);
        if (c + 3 < NCH) WRITEX(pfA, xb0); // chunk c+3
        __syncthreads();
    }

    // -------- logits(+bias) -> LDS [32][130] --------------------------------
    // 32x32 C/D layout: col = lane&31, row = (reg&3) + 8*(reg>>2) + 4*(lane>>5)
    float* logitsL = (float*)smem;
    {
        const int e  = wv * 32 + (lane & 31);
        const float bv = bias[e];
#pragma unroll
        for (int i = 0; i < 16; ++i) {
            int tok = (i & 3) + 8 * (i >> 2) + 4 * (lane >> 5);
            logitsL[tok * 130 + e] = acc[i] + bv;
        }
    }
    float*  cvf = (float*) (smem + 16640);   // [32][8]
    int*    cie = (int*)   (smem + 17664);   // [32][8]
    int*    flg = (int*)   (smem + 18688);   // [32]
    double* svd = (double*)(smem + 18816);   // [32][4]
    int*    sid = (int*)   (smem + 19840);   // [32][4]
    double* cvd = (double*)(smem + 20352);   // [8]
    __syncthreads();

    // -------- stripe top-8: thread (t, s) scans experts [s*16, s*16+16) -----
    {
        const int t = tid >> 3, s = tid & 7;
        float v[8]; int id[8];
#pragma unroll
        for (int k = 0; k < 8; ++k) { v[k] = -3.4e38f; id[k] = 0x7fffffff; }
        for (int jj = 0; jj < 16; ++jj) {
            float lv = logitsL[t * 130 + s * 16 + jj];
            int   e  = s * 16 + jj;
            bool gt[8];
#pragma unroll
            for (int k = 0; k < 8; ++k)
                gt[k] = (lv > v[k]) || (lv == v[k] && e < id[k]);
#pragma unroll
            for (int k = 7; k >= 1; --k)
                if (gt[k - 1]) { v[k] = v[k - 1]; id[k] = id[k - 1]; }
#pragma unroll
            for (int k = 0; k < 8; ++k) {
                bool put = gt[k] && (k == 0 || !gt[k - 1]);
                if (put) { v[k] = lv; id[k] = e; }
            }
        }
#pragma unroll
        for (int rd = 0; rd < 8; ++rd) {
            float hv = v[0]; int hi = id[0];
#pragma unroll
            for (int off = 1; off < 8; off <<= 1) {
                float ov = __shfl_xor(hv, off);
                int   oi = __shfl_xor(hi, off);
                if (ov > hv || (ov == hv && oi < hi)) { hv = ov; hi = oi; }
            }
            if (s == 0) { cvf[t * 8 + rd] = hv; cie[t * 8 + rd] = hi; }
            bool mine = (v[0] == hv) && (id[0] == hi);
            if (mine) {
#pragma unroll
                for (int k = 0; k < 7; ++k) { v[k] = v[k + 1]; id[k] = id[k + 1]; }
                v[7] = -3.4e38f; id[7] = 0x7fffffff;
            }
        }
    }
    __syncthreads();

    // -------- certified-gap test + fast-path fill ---------------------------
    if (tid < TM) {
        float gmin = 3.4e38f;
#pragma unroll
        for (int k = 0; k < 4; ++k)
            gmin = fminf(gmin, cvf[tid * 8 + k] - cvf[tid * 8 + k + 1]);
        flg[tid] = (gmin < TAU);
    }
    if (tid < 128) {
        int t2 = tid >> 2, k = tid & 3;
        svd[t2 * 4 + k] = (double)cvf[t2 * 8 + k];
        sid[t2 * 4 + k] = cie[t2 * 8 + k];
    }
    __syncthreads();

    // -------- rare slow path: fp64 rescore (2 candidates per wave) ----------
    for (int ts = 0; ts < TM; ++ts) {
        if (!flg[ts]) continue;              // uniform across block
#pragma unroll
        for (int h2 = 0; h2 < 2; ++h2) {
            const int cand = wv * 2 + h2;
            const int ce = cie[ts * 8 + cand];
            const float4* xr = (const float4*)(x + (size_t)(tok0 + ts) * HDIM);
            const float4* wr = (const float4*)(w + (size_t)ce * HDIM);
            double q0 = 0.0, q1 = 0.0, q2 = 0.0, q3 = 0.0;
            for (int i2 = 0; i2 < 12; ++i2) {
                int fi = lane + i2 * 64;
                if (fi < HDIM / 4) {
                    float4 xv = xr[fi];
                    float4 wv4 = wr[fi];
                    q0 = fma((double)xv.x, (double)wv4.x, q0);
                    q1 = fma((double)xv.y, (double)wv4.y, q1);
                    q2 = fma((double)xv.z, (double)wv4.z, q2);
                    q3 = fma((double)xv.w, (double)wv4.w, q3);
                }
            }
            double accd = (q0 + q2) + (q1 + q3);
#pragma unroll
            for (int off = 32; off > 0; off >>= 1)
                accd += __shfl_xor(accd, off);
            if (lane == 0) cvd[cand] = accd + (double)bias[ce];
        }
        __syncthreads();
        if (tid < 8) {                        // fp64 rank among 8 candidates
            double mv = cvd[tid]; int mi2 = cie[ts * 8 + tid];
            int rk = 0;
#pragma unroll
            for (int j2 = 0; j2 < 8; ++j2) {
                double oj = cvd[j2];
                rk += (oj > mv) || (oj == mv && cie[ts * 8 + j2] < mi2);
            }
            if (rk < 4) { svd[ts * 4 + rk] = mv; sid[ts * 4 + rk] = mi2; }
        }
        __syncthreads();
    }

    // -------- softmax + outputs ---------------------------------------------
    float* srow = (float*)smem;              // [32][128], overlays dead logits
    float4 z4 = make_float4(0.f, 0.f, 0.f, 0.f);
#pragma unroll
    for (int i = 0; i < 4; ++i)
        ((float4*)srow)[tid + i * NT] = z4;
    __syncthreads();

    if (tid < TM) {
        double m  = svd[tid * 4];
        double e0 = exp(svd[tid * 4 + 0] - m), e1 = exp(svd[tid * 4 + 1] - m);
        double e2 = exp(svd[tid * 4 + 2] - m), e3 = exp(svd[tid * 4 + 3] - m);
        double inv = 1.0 / ((e0 + e1) + (e2 + e3));
        float* oidx = out + (size_t)T_TOK * EEXP + (size_t)(tok0 + tid) * KTOP;
        int i0 = sid[tid * 4 + 0], i1 = sid[tid * 4 + 1];
        int i2 = sid[tid * 4 + 2], i3 = sid[tid * 4 + 3];
        oidx[0] = (float)i0; oidx[1] = (float)i1;
        oidx[2] = (float)i2; oidx[3] = (float)i3;
        srow[tid * EEXP + i0] = (float)(e0 * inv);
        srow[tid * EEXP + i1] = (float)(e1 * inv);
        srow[tid * EEXP + i2] = (float)(e2 * inv);
        srow[tid * EEXP + i3] = (float)(e3 * inv);
    }
    __syncthreads();

    float4* orow = (float4*)(out + (size_t)tok0 * EEXP);
#pragma unroll
    for (int i = 0; i < 4; ++i)
        orow[tid + i * NT] = ((float4*)srow)[tid + i * NT];
}

extern "C" void kernel_launch(void* const* d_in, const int* in_sizes, int n_in,
                              void* d_out, int out_size, void* d_ws, size_t ws_size,
                              hipStream_t stream) {
    const float* x    = (const float*)d_in[0];
    const float* w    = (const float*)d_in[1];
    const float* bias = (const float*)d_in[2];
    float* out        = (float*)d_out;
    char*  wp         = (char*)d_ws;   // 1440 KiB (4*180*2 tiles * 1KB)

    hipLaunchKernelGGL(w_split, dim3(180), dim3(256), 0, stream, w, wp);
    hipLaunchKernelGGL(router_fused, dim3(T_TOK / TM), dim3(NT), 0, stream,
                       x, wp, w, bias, out);
}